// Round 1
// baseline (806.142 us; speedup 1.0000x reference)
//
#include <hip/hip_runtime.h>
#include <math.h>

// GCN: 2-layer, N nodes, E edges, channels 64 -> 64 -> 32, f32 throughout.
// Pipeline: deg -> dinv -> gemm1(+selfloop init) -> scatter1 -> gemm2(+relu+b1,
// +selfloop init) -> scatter2 -> pool -> log_softmax.

#define C1 64
#define C2 32

// ---- degree: atomicAdd 1 per edge into deg[dst] (deg buffer pre-zeroed) ----
__global__ __launch_bounds__(256) void deg_kernel(const int* __restrict__ dst,
                                                  int E, float* __restrict__ deg) {
    int i = blockIdx.x * blockDim.x + threadIdx.x;
    int stride = gridDim.x * blockDim.x;
    for (int e = i; e < E; e += stride)
        atomicAdd(&deg[dst[e]], 1.0f);
}

// ---- dinv = rsqrt(deg + 1)  (the +1 is the self-loop) ----
__global__ __launch_bounds__(256) void dinv_kernel(float* __restrict__ deg, int N) {
    int i = blockIdx.x * blockDim.x + threadIdx.x;
    int stride = gridDim.x * blockDim.x;
    for (int n = i; n < N; n += stride)
        deg[n] = rsqrtf(deg[n] + 1.0f);
}

// ---- gemm1: xw = x @ W1 ; out1 = dinv^2 * xw (self-loop message, acc init) ----
// One wave per row. W1 transposed into LDS (pad 68 -> conflict-free b128 reads).
__global__ __launch_bounds__(256) void gemm1_kernel(
    const float* __restrict__ x, const float* __restrict__ W,
    const float* __restrict__ dinv,
    float* __restrict__ xw, float* __restrict__ out1, int N) {
    __shared__ __align__(16) float wt[64 * 68];
    for (int t = threadIdx.x; t < 64 * 64; t += blockDim.x) {
        int k = t >> 6, c = t & 63;
        wt[c * 68 + k] = W[t];
    }
    __syncthreads();
    int lane = threadIdx.x & 63;
    int wave = (blockIdx.x * blockDim.x + threadIdx.x) >> 6;
    int nw = (gridDim.x * blockDim.x) >> 6;
    const float4* wt4 = (const float4*)(wt + lane * 68);
    for (int n = wave; n < N; n += nw) {
        const float4* xr = (const float4*)(x + (size_t)n * C1);
        float acc = 0.f;
#pragma unroll
        for (int j = 0; j < 16; ++j) {
            float4 xx = xr[j];
            float4 ww = wt4[j];
            acc += xx.x * ww.x + xx.y * ww.y + xx.z * ww.z + xx.w * ww.w;
        }
        float di = dinv[n];
        xw[(size_t)n * C1 + lane] = acc;
        out1[(size_t)n * C1 + lane] = di * di * acc;
    }
}

// ---- scatter1: out1[dst] += dinv[s]*dinv[d] * xw[src], one wave per edge ----
__global__ __launch_bounds__(256) void scatter1_kernel(
    const int* __restrict__ src, const int* __restrict__ dst,
    const float* __restrict__ dinv, const float* __restrict__ xw,
    float* __restrict__ out1, int E) {
    int lane = threadIdx.x & 63;
    int wave = (blockIdx.x * blockDim.x + threadIdx.x) >> 6;
    int nw = (gridDim.x * blockDim.x) >> 6;
    for (int e = wave; e < E; e += nw) {
        int s = src[e], d = dst[e];
        float w = dinv[s] * dinv[d];
        float v = w * xw[(size_t)s * C1 + lane];
        atomicAdd(&out1[(size_t)d * C1 + lane], v);
    }
}

// ---- gemm2: h = relu(out1 + b1); hw = h @ W2 ; out2 = dinv^2 * hw ----
// Half-wave (32 lanes) per row.
__global__ __launch_bounds__(256) void gemm2_kernel(
    const float* __restrict__ out1, const float* __restrict__ W2,
    const float* __restrict__ b1, const float* __restrict__ dinv,
    float* __restrict__ hw, float* __restrict__ out2, int N) {
    __shared__ __align__(16) float wt[32 * 68];
    __shared__ __align__(16) float b1s[64];
    for (int t = threadIdx.x; t < 64 * 32; t += blockDim.x) {
        int k = t >> 5, c = t & 31;
        wt[c * 68 + k] = W2[t];
    }
    if (threadIdx.x < 64) b1s[threadIdx.x] = b1[threadIdx.x];
    __syncthreads();
    int c = threadIdx.x & 31;
    int hwid = (blockIdx.x * blockDim.x + threadIdx.x) >> 5;
    int nh = (gridDim.x * blockDim.x) >> 5;
    const float4* wt4 = (const float4*)(wt + c * 68);
    const float4* b14 = (const float4*)b1s;
    for (int n = hwid; n < N; n += nh) {
        const float4* hr = (const float4*)(out1 + (size_t)n * C1);
        float acc = 0.f;
#pragma unroll
        for (int j = 0; j < 16; ++j) {
            float4 hh = hr[j];
            float4 bb = b14[j];
            float4 ww = wt4[j];
            float h0 = fmaxf(hh.x + bb.x, 0.f);
            float h1 = fmaxf(hh.y + bb.y, 0.f);
            float h2 = fmaxf(hh.z + bb.z, 0.f);
            float h3 = fmaxf(hh.w + bb.w, 0.f);
            acc += h0 * ww.x + h1 * ww.y + h2 * ww.z + h3 * ww.w;
        }
        float di = dinv[n];
        hw[(size_t)n * C2 + c] = acc;
        out2[(size_t)n * C2 + c] = di * di * acc;
    }
}

// ---- scatter2: out2[dst] += norm * hw[src], half-wave per edge ----
__global__ __launch_bounds__(256) void scatter2_kernel(
    const int* __restrict__ src, const int* __restrict__ dst,
    const float* __restrict__ dinv, const float* __restrict__ hw,
    float* __restrict__ out2, int E) {
    int c = threadIdx.x & 31;
    int hwid = (blockIdx.x * blockDim.x + threadIdx.x) >> 5;
    int nh = (gridDim.x * blockDim.x) >> 5;
    for (int e = hwid; e < E; e += nh) {
        int s = src[e], d = dst[e];
        float w = dinv[s] * dinv[d];
        float v = w * hw[(size_t)s * C2 + c];
        atomicAdd(&out2[(size_t)d * C2 + c], v);
    }
}

// ---- pool: pooled[c] = sum_n out2[n][c]  (block-reduced, 1 atomic / block) ----
__global__ __launch_bounds__(256) void pool_kernel(const float* __restrict__ out2,
                                                   int N, float* __restrict__ pooled) {
    int c = threadIdx.x & 31;
    int gid = blockIdx.x * blockDim.x + threadIdx.x;
    int row0 = gid >> 5;
    int nrows = (gridDim.x * blockDim.x) >> 5;
    float acc = 0.f;
    for (int n = row0; n < N; n += nrows)
        acc += out2[(size_t)n * C2 + c];
    acc += __shfl_down(acc, 32);  // fold upper half-wave onto lower
    __shared__ float red[4][32];
    int w = threadIdx.x >> 6;
    if ((threadIdx.x & 63) < 32) red[w][c] = acc;
    __syncthreads();
    if (threadIdx.x < 32) {
        float s = red[0][c] + red[1][c] + red[2][c] + red[3][c];
        atomicAdd(&pooled[c], s);
    }
}

// ---- final: mean + b2, log_softmax over 32 classes, single wave ----
__global__ void final_kernel(const float* __restrict__ pooled,
                             const float* __restrict__ b2, int N,
                             float* __restrict__ out) {
    int c = threadIdx.x & 31;
    float v = pooled[c] / (float)N + b2[c];
    float m = v;
    for (int off = 16; off; off >>= 1) m = fmaxf(m, __shfl_xor(m, off));
    float s = __expf(v - m);
    for (int off = 16; off; off >>= 1) s += __shfl_xor(s, off);
    if (threadIdx.x < 32) out[c] = v - m - logf(s);
}

extern "C" void kernel_launch(void* const* d_in, const int* in_sizes, int n_in,
                              void* d_out, int out_size, void* d_ws, size_t ws_size,
                              hipStream_t stream) {
    const float* x  = (const float*)d_in[0];
    const int*   ei = (const int*)d_in[1];
    const float* W1 = (const float*)d_in[2];
    const float* b1 = (const float*)d_in[3];
    const float* W2 = (const float*)d_in[4];
    const float* b2 = (const float*)d_in[5];
    float* out = (float*)d_out;

    int N = in_sizes[0] / C1;
    int E = in_sizes[1] / 2;
    const int* src = ei;
    const int* dst = ei + E;

    float* ws = (float*)d_ws;
    size_t o = 0;
    float* dinv = ws + o;  o += (size_t)N;          // deg then dinv in place
    o = (o + 255) & ~(size_t)255;
    float* xw   = ws + o;  o += (size_t)N * C1;     // reused as hw after scatter1
    float* out1 = ws + o;  o += (size_t)N * C1;
    float* out2 = ws + o;  o += (size_t)N * C2;
    float* pooled = ws + o; o += 32;
    float* hwbuf = xw;

    hipMemsetAsync(dinv, 0, (size_t)N * sizeof(float), stream);
    hipMemsetAsync(pooled, 0, 32 * sizeof(float), stream);

    deg_kernel<<<1024, 256, 0, stream>>>(dst, E, dinv);
    dinv_kernel<<<(N + 255) / 256, 256, 0, stream>>>(dinv, N);
    gemm1_kernel<<<512, 256, 0, stream>>>(x, W1, dinv, xw, out1, N);
    scatter1_kernel<<<2048, 256, 0, stream>>>(src, dst, dinv, xw, out1, E);
    gemm2_kernel<<<512, 256, 0, stream>>>(out1, W2, b1, dinv, hwbuf, out2, N);
    scatter2_kernel<<<2048, 256, 0, stream>>>(src, dst, dinv, hwbuf, out2, E);
    pool_kernel<<<256, 256, 0, stream>>>(out2, N, pooled);
    final_kernel<<<1, 64, 0, stream>>>(pooled, b2, N, out);
}

// Round 2
// 536.566 us; speedup vs baseline: 1.5024x; 1.5024x over previous
//
#include <hip/hip_runtime.h>
#include <math.h>

// GCN 2-layer, N nodes, E edges, 64 -> 64 -> 32 channels, f32.
// R2: counting-sort edges by dst (deg histogram -> scan -> reorder), then
// gather-based aggregation (no f32 atomics): out[n] = dinv[n]^2*xw[n] +
// sum_{e in run(n)} w_e * xw[src_e].

#define C1 64
#define C2 32

// ---- degree histogram: integer atomics into deg[dst] (pre-zeroed) ----
__global__ __launch_bounds__(256) void deg_kernel(const int* __restrict__ dst,
                                                  int E, unsigned* __restrict__ deg) {
    int i = blockIdx.x * blockDim.x + threadIdx.x;
    int stride = gridDim.x * blockDim.x;
    for (int e = i; e < E; e += stride)
        atomicAdd(&deg[dst[e]], 1u);
}

// ---- dinv = rsqrt(deg + 1)  (+1 is the self-loop) ----
__global__ __launch_bounds__(256) void dinv_kernel(const unsigned* __restrict__ deg,
                                                   float* __restrict__ dinv, int N) {
    int i = blockIdx.x * blockDim.x + threadIdx.x;
    int stride = gridDim.x * blockDim.x;
    for (int n = i; n < N; n += stride)
        dinv[n] = rsqrtf((float)deg[n] + 1.0f);
}

// ---- scan step A: per-block (256) sums of deg ----
__global__ __launch_bounds__(256) void scanA_kernel(const unsigned* __restrict__ deg,
                                                    int N, unsigned* __restrict__ partials) {
    __shared__ unsigned s[256];
    int i = blockIdx.x * 256 + threadIdx.x;
    unsigned v = (i < N) ? deg[i] : 0u;
    s[threadIdx.x] = v;
    __syncthreads();
    for (int st = 128; st; st >>= 1) {
        if (threadIdx.x < st) s[threadIdx.x] += s[threadIdx.x + st];
        __syncthreads();
    }
    if (threadIdx.x == 0) partials[blockIdx.x] = s[0];
}

// ---- scan step B: exclusive scan of partials (single block, nb <= 512) ----
__global__ __launch_bounds__(512) void scanB_kernel(unsigned* __restrict__ partials, int nb) {
    __shared__ unsigned s[512];
    unsigned v = (threadIdx.x < (unsigned)nb) ? partials[threadIdx.x] : 0u;
    s[threadIdx.x] = v;
    __syncthreads();
    for (int st = 1; st < 512; st <<= 1) {
        unsigned t = s[threadIdx.x];
        if ((int)threadIdx.x >= st) t += s[threadIdx.x - st];
        __syncthreads();
        s[threadIdx.x] = t;
        __syncthreads();
    }
    if (threadIdx.x < (unsigned)nb) partials[threadIdx.x] = s[threadIdx.x] - v;
}

// ---- scan step C: in-block exclusive scan + partial offset -> off, cursor ----
__global__ __launch_bounds__(256) void scanC_kernel(const unsigned* __restrict__ deg,
                                                    const unsigned* __restrict__ partials,
                                                    int N, int* __restrict__ off,
                                                    int* __restrict__ cursor) {
    __shared__ unsigned s[256];
    int i = blockIdx.x * 256 + threadIdx.x;
    unsigned v = (i < N) ? deg[i] : 0u;
    s[threadIdx.x] = v;
    __syncthreads();
    for (int st = 1; st < 256; st <<= 1) {
        unsigned t = s[threadIdx.x];
        if ((int)threadIdx.x >= st) t += s[threadIdx.x - st];
        __syncthreads();
        s[threadIdx.x] = t;
        __syncthreads();
    }
    if (i < N) {
        int excl = (int)(s[threadIdx.x] - v + partials[blockIdx.x]);
        off[i] = excl;
        cursor[i] = excl;
    }
}

// ---- reorder: bucket edges by dst; ep[pos] = (norm, src) ----
__global__ __launch_bounds__(256) void reorder_kernel(
    const int* __restrict__ src, const int* __restrict__ dst,
    const float* __restrict__ dinv, int* __restrict__ cursor,
    float2* __restrict__ ep, int E) {
    int i = blockIdx.x * blockDim.x + threadIdx.x;
    int stride = gridDim.x * blockDim.x;
    for (int e = i; e < E; e += stride) {
        int s = src[e], d = dst[e];
        float w = dinv[s] * dinv[d];
        int pos = atomicAdd(&cursor[d], 1);
        ep[pos] = make_float2(w, __int_as_float(s));
    }
}

// ---- gemm1: xw = x @ W1 (one wave per row, W1^T staged in LDS pad 68) ----
__global__ __launch_bounds__(256) void gemm1_kernel(
    const float* __restrict__ x, const float* __restrict__ W,
    float* __restrict__ xw, int N) {
    __shared__ __align__(16) float wt[64 * 68];
    for (int t = threadIdx.x; t < 64 * 64; t += blockDim.x) {
        int k = t >> 6, c = t & 63;
        wt[c * 68 + k] = W[t];
    }
    __syncthreads();
    int lane = threadIdx.x & 63;
    int wave = (blockIdx.x * blockDim.x + threadIdx.x) >> 6;
    int nw = (gridDim.x * blockDim.x) >> 6;
    const float4* wt4 = (const float4*)(wt + lane * 68);
    for (int n = wave; n < N; n += nw) {
        const float4* xr = (const float4*)(x + (size_t)n * C1);
        float acc = 0.f;
#pragma unroll
        for (int j = 0; j < 16; ++j) {
            float4 xx = xr[j];
            float4 ww = wt4[j];
            acc += xx.x * ww.x + xx.y * ww.y + xx.z * ww.z + xx.w * ww.w;
        }
        xw[(size_t)n * C1 + lane] = acc;
    }
}

// ---- gather1: out1[n] = dinv[n]^2*xw[n] + sum_e w_e * xw[src_e]  (wave/node) ----
__global__ __launch_bounds__(256) void gather1_kernel(
    const float* __restrict__ xw, const float2* __restrict__ ep,
    const int* __restrict__ off, const int* __restrict__ cursor,
    const float* __restrict__ dinv, float* __restrict__ out1, int N) {
    int lane = threadIdx.x & 63;
    int wave = (blockIdx.x * blockDim.x + threadIdx.x) >> 6;
    int nw = (gridDim.x * blockDim.x) >> 6;
    for (int n = wave; n < N; n += nw) {
        float di = dinv[n];
        float acc = di * di * xw[(size_t)n * C1 + lane];
        int e = off[n], e1 = cursor[n];
        for (; e + 1 < e1; e += 2) {
            float2 p0 = ep[e];
            float2 p1 = ep[e + 1];
            int s0 = __float_as_int(p0.y);
            int s1 = __float_as_int(p1.y);
            float v0 = xw[(size_t)s0 * C1 + lane];
            float v1 = xw[(size_t)s1 * C1 + lane];
            acc += p0.x * v0 + p1.x * v1;
        }
        if (e < e1) {
            float2 p = ep[e];
            acc += p.x * xw[(size_t)__float_as_int(p.y) * C1 + lane];
        }
        out1[(size_t)n * C1 + lane] = acc;
    }
}

// ---- gemm2: h = relu(out1 + b1); hw = h @ W2 (half-wave per row) ----
__global__ __launch_bounds__(256) void gemm2_kernel(
    const float* __restrict__ out1, const float* __restrict__ W2,
    const float* __restrict__ b1, float* __restrict__ hw, int N) {
    __shared__ __align__(16) float wt[32 * 68];
    __shared__ __align__(16) float b1s[64];
    for (int t = threadIdx.x; t < 64 * 32; t += blockDim.x) {
        int k = t >> 5, c = t & 31;
        wt[c * 68 + k] = W2[t];
    }
    if (threadIdx.x < 64) b1s[threadIdx.x] = b1[threadIdx.x];
    __syncthreads();
    int c = threadIdx.x & 31;
    int hwid = (blockIdx.x * blockDim.x + threadIdx.x) >> 5;
    int nh = (gridDim.x * blockDim.x) >> 5;
    const float4* wt4 = (const float4*)(wt + c * 68);
    const float4* b14 = (const float4*)b1s;
    for (int n = hwid; n < N; n += nh) {
        const float4* hr = (const float4*)(out1 + (size_t)n * C1);
        float acc = 0.f;
#pragma unroll
        for (int j = 0; j < 16; ++j) {
            float4 hh = hr[j];
            float4 bb = b14[j];
            float4 ww = wt4[j];
            float h0 = fmaxf(hh.x + bb.x, 0.f);
            float h1 = fmaxf(hh.y + bb.y, 0.f);
            float h2 = fmaxf(hh.z + bb.z, 0.f);
            float h3 = fmaxf(hh.w + bb.w, 0.f);
            acc += h0 * ww.x + h1 * ww.y + h2 * ww.z + h3 * ww.w;
        }
        hw[(size_t)n * C2 + c] = acc;
    }
}

// ---- gather2: out2[n] = dinv[n]^2*hw[n] + sum_e w_e*hw[src_e]  (half-wave/node) ----
__global__ __launch_bounds__(256) void gather2_kernel(
    const float* __restrict__ hw, const float2* __restrict__ ep,
    const int* __restrict__ off, const int* __restrict__ cursor,
    const float* __restrict__ dinv, float* __restrict__ out2, int N) {
    int c = threadIdx.x & 31;
    int hwid = (blockIdx.x * blockDim.x + threadIdx.x) >> 5;
    int nh = (gridDim.x * blockDim.x) >> 5;
    for (int n = hwid; n < N; n += nh) {
        float di = dinv[n];
        float acc = di * di * hw[(size_t)n * C2 + c];
        int e = off[n], e1 = cursor[n];
        for (; e + 1 < e1; e += 2) {
            float2 p0 = ep[e];
            float2 p1 = ep[e + 1];
            float v0 = hw[(size_t)__float_as_int(p0.y) * C2 + c];
            float v1 = hw[(size_t)__float_as_int(p1.y) * C2 + c];
            acc += p0.x * v0 + p1.x * v1;
        }
        if (e < e1) {
            float2 p = ep[e];
            acc += p.x * hw[(size_t)__float_as_int(p.y) * C2 + c];
        }
        out2[(size_t)n * C2 + c] = acc;
    }
}

// ---- pool: pooled[c] = sum_n out2[n][c] (block-reduced, 1 atomic/block) ----
__global__ __launch_bounds__(256) void pool_kernel(const float* __restrict__ out2,
                                                   int N, float* __restrict__ pooled) {
    int c = threadIdx.x & 31;
    int gid = blockIdx.x * blockDim.x + threadIdx.x;
    int row0 = gid >> 5;
    int nrows = (gridDim.x * blockDim.x) >> 5;
    float acc = 0.f;
    for (int n = row0; n < N; n += nrows)
        acc += out2[(size_t)n * C2 + c];
    acc += __shfl_down(acc, 32);
    __shared__ float red[4][32];
    int w = threadIdx.x >> 6;
    if ((threadIdx.x & 63) < 32) red[w][c] = acc;
    __syncthreads();
    if (threadIdx.x < 32) {
        float s = red[0][c] + red[1][c] + red[2][c] + red[3][c];
        atomicAdd(&pooled[c], s);
    }
}

// ---- final: mean + b2, log_softmax over 32 classes ----
__global__ void final_kernel(const float* __restrict__ pooled,
                             const float* __restrict__ b2, int N,
                             float* __restrict__ out) {
    int c = threadIdx.x & 31;
    float v = pooled[c] / (float)N + b2[c];
    float m = v;
    for (int off = 16; off; off >>= 1) m = fmaxf(m, __shfl_xor(m, off));
    float s = __expf(v - m);
    for (int off = 16; off; off >>= 1) s += __shfl_xor(s, off);
    if (threadIdx.x < 32) out[c] = v - m - logf(s);
}

extern "C" void kernel_launch(void* const* d_in, const int* in_sizes, int n_in,
                              void* d_out, int out_size, void* d_ws, size_t ws_size,
                              hipStream_t stream) {
    const float* x  = (const float*)d_in[0];
    const int*   ei = (const int*)d_in[1];
    const float* W1 = (const float*)d_in[2];
    const float* b1 = (const float*)d_in[3];
    const float* W2 = (const float*)d_in[4];
    const float* b2 = (const float*)d_in[5];
    float* out = (float*)d_out;

    int N = in_sizes[0] / C1;
    int E = in_sizes[1] / 2;
    const int* src = ei;
    const int* dst = ei + E;
    int nb = (N + 255) / 256;  // <= 512

    char* ws = (char*)d_ws;
    size_t o = 0;
    auto alloc = [&](size_t bytes) { void* p = ws + o; o = (o + bytes + 255) & ~(size_t)255; return p; };
    unsigned* deg    = (unsigned*)alloc((size_t)N * 4);
    float*    dinv   = (float*)alloc((size_t)N * 4);
    int*      off    = (int*)alloc((size_t)N * 4);
    int*      cursor = (int*)alloc((size_t)N * 4);
    unsigned* parts  = (unsigned*)alloc(512 * 4);
    float*    pooled = (float*)alloc(32 * 4);
    float*    xw     = (float*)alloc((size_t)N * C1 * 4);  // reused as hw
    float*    out1   = (float*)alloc((size_t)N * C1 * 4);
    float*    out2   = (float*)alloc((size_t)N * C2 * 4);
    float2*   ep     = (float2*)alloc((size_t)E * 8);
    float*    hwbuf  = xw;

    hipMemsetAsync(deg, 0, (size_t)N * 4, stream);
    hipMemsetAsync(pooled, 0, 32 * 4, stream);

    deg_kernel<<<1024, 256, 0, stream>>>(dst, E, deg);
    dinv_kernel<<<nb, 256, 0, stream>>>(deg, dinv, N);
    scanA_kernel<<<nb, 256, 0, stream>>>(deg, N, parts);
    scanB_kernel<<<1, 512, 0, stream>>>(parts, nb);
    scanC_kernel<<<nb, 256, 0, stream>>>(deg, parts, N, off, cursor);
    reorder_kernel<<<2048, 256, 0, stream>>>(src, dst, dinv, cursor, ep, E);
    gemm1_kernel<<<1024, 256, 0, stream>>>(x, W1, xw, N);
    gather1_kernel<<<6144, 256, 0, stream>>>(xw, ep, off, cursor, dinv, out1, N);
    gemm2_kernel<<<1024, 256, 0, stream>>>(out1, W2, b1, hwbuf, N);
    gather2_kernel<<<4096, 256, 0, stream>>>(hwbuf, ep, off, cursor, dinv, out2, N);
    pool_kernel<<<256, 256, 0, stream>>>(out2, N, pooled);
    final_kernel<<<1, 64, 0, stream>>>(pooled, b2, N, out);
}

// Round 3
// 525.559 us; speedup vs baseline: 1.5339x; 1.0209x over previous
//
#include <hip/hip_runtime.h>
#include <math.h>

// GCN 2-layer, N nodes, E edges, 64 -> 64 -> 32 channels.
// R3: norm factorization (ep stores src index only, rows pre-scaled by dinv),
// bf16 gather arrays (xws/hws), pool fused into gather2.

#define C1 64
#define C2 32

__device__ __forceinline__ unsigned short f2bf(float f) {
    unsigned u = __float_as_uint(f);
    u = (u + 0x7FFFu + ((u >> 16) & 1u)) >> 16;
    return (unsigned short)u;
}
__device__ __forceinline__ float bf2f(unsigned short u) {
    return __uint_as_float((unsigned)u << 16);
}

// ---- degree histogram: integer atomics into deg[dst] (pre-zeroed) ----
__global__ __launch_bounds__(256) void deg_kernel(const int* __restrict__ dst,
                                                  int E, unsigned* __restrict__ deg) {
    int i = blockIdx.x * blockDim.x + threadIdx.x;
    int stride = gridDim.x * blockDim.x;
    for (int e = i; e < E; e += stride)
        atomicAdd(&deg[dst[e]], 1u);
}

// ---- dinv = rsqrt(deg + 1)  (+1 is the self-loop) ----
__global__ __launch_bounds__(256) void dinv_kernel(const unsigned* __restrict__ deg,
                                                   float* __restrict__ dinv, int N) {
    int i = blockIdx.x * blockDim.x + threadIdx.x;
    int stride = gridDim.x * blockDim.x;
    for (int n = i; n < N; n += stride)
        dinv[n] = rsqrtf((float)deg[n] + 1.0f);
}

// ---- scan step A: per-block (256) sums of deg ----
__global__ __launch_bounds__(256) void scanA_kernel(const unsigned* __restrict__ deg,
                                                    int N, unsigned* __restrict__ partials) {
    __shared__ unsigned s[256];
    int i = blockIdx.x * 256 + threadIdx.x;
    unsigned v = (i < N) ? deg[i] : 0u;
    s[threadIdx.x] = v;
    __syncthreads();
    for (int st = 128; st; st >>= 1) {
        if (threadIdx.x < st) s[threadIdx.x] += s[threadIdx.x + st];
        __syncthreads();
    }
    if (threadIdx.x == 0) partials[blockIdx.x] = s[0];
}

// ---- scan step B: exclusive scan of partials (single block, nb <= 512) ----
__global__ __launch_bounds__(512) void scanB_kernel(unsigned* __restrict__ partials, int nb) {
    __shared__ unsigned s[512];
    unsigned v = (threadIdx.x < (unsigned)nb) ? partials[threadIdx.x] : 0u;
    s[threadIdx.x] = v;
    __syncthreads();
    for (int st = 1; st < 512; st <<= 1) {
        unsigned t = s[threadIdx.x];
        if ((int)threadIdx.x >= st) t += s[threadIdx.x - st];
        __syncthreads();
        s[threadIdx.x] = t;
        __syncthreads();
    }
    if (threadIdx.x < (unsigned)nb) partials[threadIdx.x] = s[threadIdx.x] - v;
}

// ---- scan step C: in-block exclusive scan + partial offset -> off, cursor ----
__global__ __launch_bounds__(256) void scanC_kernel(const unsigned* __restrict__ deg,
                                                    const unsigned* __restrict__ partials,
                                                    int N, int* __restrict__ off,
                                                    int* __restrict__ cursor) {
    __shared__ unsigned s[256];
    int i = blockIdx.x * 256 + threadIdx.x;
    unsigned v = (i < N) ? deg[i] : 0u;
    s[threadIdx.x] = v;
    __syncthreads();
    for (int st = 1; st < 256; st <<= 1) {
        unsigned t = s[threadIdx.x];
        if ((int)threadIdx.x >= st) t += s[threadIdx.x - st];
        __syncthreads();
        s[threadIdx.x] = t;
        __syncthreads();
    }
    if (i < N) {
        int excl = (int)(s[threadIdx.x] - v + partials[blockIdx.x]);
        off[i] = excl;
        cursor[i] = excl;
    }
}

// ---- reorder: bucket edges by dst; ep[pos] = src (4 B payload only) ----
__global__ __launch_bounds__(256) void reorder_kernel(
    const int* __restrict__ src, const int* __restrict__ dst,
    int* __restrict__ cursor, int* __restrict__ ep, int E) {
    int i = blockIdx.x * blockDim.x + threadIdx.x;
    int stride = gridDim.x * blockDim.x;
    for (int e = i; e < E; e += stride) {
        int s = src[e], d = dst[e];
        int pos = atomicAdd(&cursor[d], 1);
        ep[pos] = s;
    }
}

// ---- gemm1: xws = dinv * (x @ W1), stored bf16 (one wave per row) ----
__global__ __launch_bounds__(256) void gemm1_kernel(
    const float* __restrict__ x, const float* __restrict__ W,
    const float* __restrict__ dinv, unsigned short* __restrict__ xws, int N) {
    __shared__ __align__(16) float wt[64 * 68];
    for (int t = threadIdx.x; t < 64 * 64; t += blockDim.x) {
        int k = t >> 6, c = t & 63;
        wt[c * 68 + k] = W[t];
    }
    __syncthreads();
    int lane = threadIdx.x & 63;
    int wave = (blockIdx.x * blockDim.x + threadIdx.x) >> 6;
    int nw = (gridDim.x * blockDim.x) >> 6;
    const float4* wt4 = (const float4*)(wt + lane * 68);
    for (int n = wave; n < N; n += nw) {
        const float4* xr = (const float4*)(x + (size_t)n * C1);
        float acc = 0.f;
#pragma unroll
        for (int j = 0; j < 16; ++j) {
            float4 xx = xr[j];
            float4 ww = wt4[j];
            acc += xx.x * ww.x + xx.y * ww.y + xx.z * ww.z + xx.w * ww.w;
        }
        xws[(size_t)n * C1 + lane] = f2bf(dinv[n] * acc);
    }
}

// ---- gather1: out1[n] = dinv[n]*(sum_e xws[src_e] + dinv[n]*xws[n]) ----
// Half-wave (32 lanes) per node, 2 channels per lane (ushort2).
__global__ __launch_bounds__(256) void gather1_kernel(
    const ushort2* __restrict__ xws2, const int* __restrict__ ep,
    const int* __restrict__ off, const int* __restrict__ cursor,
    const float* __restrict__ dinv, float2* __restrict__ out1, int N) {
    int lane = threadIdx.x & 63;
    int c2 = lane & 31;
    int slot = (((blockIdx.x * blockDim.x + threadIdx.x) >> 6) << 1) + (lane >> 5);
    int nslots = (gridDim.x * blockDim.x) >> 5;
    for (int n = slot; n < N; n += nslots) {
        float di = dinv[n];
        ushort2 sv = xws2[(size_t)n * 32 + c2];
        float a0 = di * bf2f(sv.x), a1 = di * bf2f(sv.y);
        int e = off[n], e1 = cursor[n];
        for (; e + 3 < e1; e += 4) {
            int s0 = ep[e], s1 = ep[e + 1], s2 = ep[e + 2], s3 = ep[e + 3];
            ushort2 v0 = xws2[(size_t)s0 * 32 + c2];
            ushort2 v1 = xws2[(size_t)s1 * 32 + c2];
            ushort2 v2 = xws2[(size_t)s2 * 32 + c2];
            ushort2 v3 = xws2[(size_t)s3 * 32 + c2];
            a0 += bf2f(v0.x) + bf2f(v1.x) + bf2f(v2.x) + bf2f(v3.x);
            a1 += bf2f(v0.y) + bf2f(v1.y) + bf2f(v2.y) + bf2f(v3.y);
        }
        for (; e < e1; ++e) {
            ushort2 v = xws2[(size_t)ep[e] * 32 + c2];
            a0 += bf2f(v.x);
            a1 += bf2f(v.y);
        }
        out1[(size_t)n * 32 + c2] = make_float2(di * a0, di * a1);
    }
}

// ---- gemm2: hws = dinv * (relu(out1 + b1) @ W2), stored bf16 (half-wave/row) ----
__global__ __launch_bounds__(256) void gemm2_kernel(
    const float* __restrict__ out1, const float* __restrict__ W2,
    const float* __restrict__ b1, const float* __restrict__ dinv,
    unsigned short* __restrict__ hws, int N) {
    __shared__ __align__(16) float wt[32 * 68];
    __shared__ __align__(16) float b1s[64];
    for (int t = threadIdx.x; t < 64 * 32; t += blockDim.x) {
        int k = t >> 5, c = t & 31;
        wt[c * 68 + k] = W2[t];
    }
    if (threadIdx.x < 64) b1s[threadIdx.x] = b1[threadIdx.x];
    __syncthreads();
    int c = threadIdx.x & 31;
    int hwid = (blockIdx.x * blockDim.x + threadIdx.x) >> 5;
    int nh = (gridDim.x * blockDim.x) >> 5;
    const float4* wt4 = (const float4*)(wt + c * 68);
    const float4* b14 = (const float4*)b1s;
    for (int n = hwid; n < N; n += nh) {
        const float4* hr = (const float4*)(out1 + (size_t)n * C1);
        float acc = 0.f;
#pragma unroll
        for (int j = 0; j < 16; ++j) {
            float4 hh = hr[j];
            float4 bb = b14[j];
            float4 ww = wt4[j];
            float h0 = fmaxf(hh.x + bb.x, 0.f);
            float h1 = fmaxf(hh.y + bb.y, 0.f);
            float h2 = fmaxf(hh.z + bb.z, 0.f);
            float h3 = fmaxf(hh.w + bb.w, 0.f);
            acc += h0 * ww.x + h1 * ww.y + h2 * ww.z + h3 * ww.w;
        }
        hws[(size_t)n * C2 + c] = f2bf(dinv[n] * acc);
    }
}

// ---- gather2 + fused pool: pooled[c] += sum_n dinv[n]*(sum_e hws[src_e] + dinv[n]*hws[n]) ----
// Quarter-wave (16 lanes) per node, 2 channels per lane.
__global__ __launch_bounds__(256) void gather2_kernel(
    const ushort2* __restrict__ hws2, const int* __restrict__ ep,
    const int* __restrict__ off, const int* __restrict__ cursor,
    const float* __restrict__ dinv, float* __restrict__ pooled, int N) {
    __shared__ float ps[32];
    if (threadIdx.x < 32) ps[threadIdx.x] = 0.f;
    __syncthreads();
    int lane = threadIdx.x & 63;
    int c2 = lane & 15;
    int slot = (((blockIdx.x * blockDim.x + threadIdx.x) >> 6) << 2) + (lane >> 4);
    int nslots = (gridDim.x * blockDim.x) >> 4;
    float p0 = 0.f, p1 = 0.f;
    for (int n = slot; n < N; n += nslots) {
        float di = dinv[n];
        ushort2 sv = hws2[(size_t)n * 16 + c2];
        float a0 = di * bf2f(sv.x), a1 = di * bf2f(sv.y);
        int e = off[n], e1 = cursor[n];
        for (; e + 3 < e1; e += 4) {
            int s0 = ep[e], s1 = ep[e + 1], s2 = ep[e + 2], s3 = ep[e + 3];
            ushort2 v0 = hws2[(size_t)s0 * 16 + c2];
            ushort2 v1 = hws2[(size_t)s1 * 16 + c2];
            ushort2 v2 = hws2[(size_t)s2 * 16 + c2];
            ushort2 v3 = hws2[(size_t)s3 * 16 + c2];
            a0 += bf2f(v0.x) + bf2f(v1.x) + bf2f(v2.x) + bf2f(v3.x);
            a1 += bf2f(v0.y) + bf2f(v1.y) + bf2f(v2.y) + bf2f(v3.y);
        }
        for (; e < e1; ++e) {
            ushort2 v = hws2[(size_t)ep[e] * 16 + c2];
            a0 += bf2f(v.x);
            a1 += bf2f(v.y);
        }
        p0 += di * a0;
        p1 += di * a1;
    }
    atomicAdd(&ps[2 * c2], p0);
    atomicAdd(&ps[2 * c2 + 1], p1);
    __syncthreads();
    if (threadIdx.x < 32) atomicAdd(&pooled[threadIdx.x], ps[threadIdx.x]);
}

// ---- final: mean + b2, log_softmax over 32 classes ----
__global__ void final_kernel(const float* __restrict__ pooled,
                             const float* __restrict__ b2, int N,
                             float* __restrict__ out) {
    int c = threadIdx.x & 31;
    float v = pooled[c] / (float)N + b2[c];
    float m = v;
    for (int off = 16; off; off >>= 1) m = fmaxf(m, __shfl_xor(m, off));
    float s = __expf(v - m);
    for (int off = 16; off; off >>= 1) s += __shfl_xor(s, off);
    if (threadIdx.x < 32) out[c] = v - m - logf(s);
}

extern "C" void kernel_launch(void* const* d_in, const int* in_sizes, int n_in,
                              void* d_out, int out_size, void* d_ws, size_t ws_size,
                              hipStream_t stream) {
    const float* x  = (const float*)d_in[0];
    const int*   ei = (const int*)d_in[1];
    const float* W1 = (const float*)d_in[2];
    const float* b1 = (const float*)d_in[3];
    const float* W2 = (const float*)d_in[4];
    const float* b2 = (const float*)d_in[5];
    float* out = (float*)d_out;

    int N = in_sizes[0] / C1;
    int E = in_sizes[1] / 2;
    const int* src = ei;
    const int* dst = ei + E;
    int nb = (N + 255) / 256;  // <= 512

    char* ws = (char*)d_ws;
    size_t o = 0;
    auto alloc = [&](size_t bytes) { void* p = ws + o; o = (o + bytes + 255) & ~(size_t)255; return p; };
    unsigned*       deg    = (unsigned*)alloc((size_t)N * 4);
    float*          dinv   = (float*)alloc((size_t)N * 4);
    int*            off    = (int*)alloc((size_t)N * 4);
    int*            cursor = (int*)alloc((size_t)N * 4);
    unsigned*       parts  = (unsigned*)alloc(512 * 4);
    float*          pooled = (float*)alloc(32 * 4);
    unsigned short* xws    = (unsigned short*)alloc((size_t)N * C1 * 2);  // bf16, reused as hws
    float*          out1   = (float*)alloc((size_t)N * C1 * 4);
    int*            ep     = (int*)alloc((size_t)E * 4);
    unsigned short* hws    = xws;

    hipMemsetAsync(deg, 0, (size_t)N * 4, stream);
    hipMemsetAsync(pooled, 0, 32 * 4, stream);

    deg_kernel<<<1024, 256, 0, stream>>>(dst, E, deg);
    dinv_kernel<<<nb, 256, 0, stream>>>(deg, dinv, N);
    scanA_kernel<<<nb, 256, 0, stream>>>(deg, N, parts);
    scanB_kernel<<<1, 512, 0, stream>>>(parts, nb);
    scanC_kernel<<<nb, 256, 0, stream>>>(deg, parts, N, off, cursor);
    reorder_kernel<<<2048, 256, 0, stream>>>(src, dst, cursor, ep, E);
    gemm1_kernel<<<1024, 256, 0, stream>>>(x, W1, dinv, xws, N);
    gather1_kernel<<<6144, 256, 0, stream>>>((const ushort2*)xws, ep, off, cursor, dinv,
                                             (float2*)out1, N);
    gemm2_kernel<<<1024, 256, 0, stream>>>(out1, W2, b1, dinv, hws, N);
    gather2_kernel<<<4096, 256, 0, stream>>>((const ushort2*)hws, ep, off, cursor, dinv,
                                             pooled, N);
    final_kernel<<<1, 64, 0, stream>>>(pooled, b2, N, out);
}